// Round 1
// baseline (229.177 us; speedup 1.0000x reference)
//
#include <hip/hip_runtime.h>

// MuliHeadedMaskedSelfAttention: B=2, T=2048, C=1024, H=16, DK=64, OUT=1024
// Logit path (Q/K projection, QK^T) in split-bf16; V/P/O bf16. Q pre-scaled by 8.
// R11: QKV + output GEMMs rewritten as a 256x128-tile, BK=64, 8-wave,
// 4-phase/2-K-tile pipelined kernel (counted vmcnt, XOR-swizzled LDS,
// setprio around MFMA clusters). Q/K split-bf16 expressed as a virtual
// K'=3072 contraction over regions [Xh*Wh | Xh*Wl | Xl*Wh].

typedef unsigned short u16;
typedef unsigned int u32;
typedef unsigned long long u64;
typedef __attribute__((ext_vector_type(8))) short bf16x8;
typedef __attribute__((ext_vector_type(4))) float f32x4;

__device__ inline u16 f2bf(float f) {
  union { float f; unsigned u; } v; v.f = f;
  unsigned r = v.u + 0x7FFFu + ((v.u >> 16) & 1u);  // RNE
  return (u16)(r >> 16);
}
__device__ inline float bf2f(u16 h) {
  union { unsigned u; float f; } v; v.u = ((unsigned)h) << 16;
  return v.f;
}
__device__ inline void glds16(const u16* g, u16* s) {
  __builtin_amdgcn_global_load_lds(
      (const __attribute__((address_space(1))) u32*)g,
      (__attribute__((address_space(3))) u32*)s, 16, 0, 0);
}
#define MFMA __builtin_amdgcn_mfma_f32_16x16x32_bf16

// ---- fused prologue. z=0: split-cast x. z=1,2: split-transpose wq,wk.
// z=3,4: plain transpose wv,wo.
__global__ __launch_bounds__(256) void prep(
    const float* __restrict__ x,
    const float* __restrict__ wq, const float* __restrict__ wk,
    const float* __restrict__ wv, const float* __restrict__ wo,
    u16* __restrict__ Xh, u16* __restrict__ Xl,
    u16* __restrict__ Wqh, u16* __restrict__ Wql,
    u16* __restrict__ Wkh, u16* __restrict__ Wkl,
    u16* __restrict__ Wvt, u16* __restrict__ Wot) {
  const int z = blockIdx.z;
  const int tid = threadIdx.x;
  if (z == 0) {
    const int bid = blockIdx.y * 32 + blockIdx.x;
#pragma unroll
    for (int k = 0; k < 4; k++) {
      int i = bid * 4096 + k * 1024 + tid * 4;
      float4 v = *(const float4*)(x + i);
      ushort4 h, l;
      h.x = f2bf(v.x); l.x = f2bf(v.x - bf2f(h.x));
      h.y = f2bf(v.y); l.y = f2bf(v.y - bf2f(h.y));
      h.z = f2bf(v.z); l.z = f2bf(v.z - bf2f(h.z));
      h.w = f2bf(v.w); l.w = f2bf(v.w - bf2f(h.w));
      *(ushort4*)(Xh + i) = h;
      *(ushort4*)(Xl + i) = l;
    }
    return;
  }
  __shared__ float tile[32][33];
  const float* W = (z == 1) ? wq : (z == 2) ? wk : (z == 3) ? wv : wo;
  const int bx = blockIdx.x * 32, by = blockIdx.y * 32;
  const int tx = tid & 31, ty = tid >> 5;
#pragma unroll
  for (int j = 0; j < 32; j += 8)
    tile[ty + j][tx] = W[(size_t)(by + ty + j) * 1024 + bx + tx];
  __syncthreads();
  if (z <= 2) {
    u16* Th = (z == 1) ? Wqh : Wkh;
    u16* Tl = (z == 1) ? Wql : Wkl;
#pragma unroll
    for (int j = 0; j < 32; j += 8) {
      float v = tile[tx][ty + j];
      u16 h = f2bf(v);
      size_t idx = (size_t)(bx + ty + j) * 1024 + by + tx;
      Th[idx] = h;
      Tl[idx] = f2bf(v - bf2f(h));
    }
  } else {
    u16* T = (z == 3) ? Wvt : Wot;
#pragma unroll
    for (int j = 0; j < 32; j += 8)
      T[(size_t)(bx + ty + j) * 1024 + by + tx] = f2bf(tile[tx][ty + j]);
  }
}

// ---- 256x128-tile BK=64 pipelined GEMM, 8 waves (4M x 2N), 4 phases per
// 2 K-tiles, counted vmcnt (never 0 in steady state), XOR-swizzled LDS.
// MODE 0: z=0 Q (K'=3072 over [Xh*Wqh|Xh*Wql|Xl*Wqh], scale 8, split-store)
//         z=1 K (same with Wk), z=2 V (K'=1024, V^T store).
// MODE 1: out GEMM fp32 C = O16[4096,1024] x Wot[1024,1024]^T.
#define BAR() do { asm volatile("" ::: "memory"); __builtin_amdgcn_s_barrier(); asm volatile("" ::: "memory"); } while (0)
#define WAITV(N) asm volatile("s_waitcnt vmcnt(" #N ")" ::: "memory")
#define SP(P) __builtin_amdgcn_s_setprio(P)

template <int MODE>
__global__ __launch_bounds__(512, 2) void gemm3(
    const u16* __restrict__ Ah_, const u16* __restrict__ Al_,
    const u16* __restrict__ BQh, const u16* __restrict__ BQl,
    const u16* __restrict__ BKh, const u16* __restrict__ BKl,
    const u16* __restrict__ BVt,
    u16* __restrict__ Qh, u16* __restrict__ Ql,
    u16* __restrict__ Kh, u16* __restrict__ Kl,
    u16* __restrict__ Vt, float* __restrict__ Cout) {
  __shared__ __align__(16) u16 As[2][256][64];  // 64KB
  __shared__ __align__(16) u16 Bs[2][128][64];  // 32KB
  const int z = (MODE == 0) ? blockIdx.z : 3;
  const u16* Bh_ = (MODE == 1) ? BQh : (z == 0) ? BQh : (z == 1) ? BKh : BVt;
  const u16* Bl_ = (z == 0) ? BQl : (z == 1) ? BKl : Bh_;
  const int NT = (MODE == 0 && z < 2) ? 48 : 16;  // K-tiles of 64
  const int tid = threadIdx.x;
  const int lane = tid & 63, wid = tid >> 6;
  const int quad = lane >> 4, lc = lane & 15, l7 = lane & 7;
  const int m0 = blockIdx.y * 256, n0 = blockIdx.x * 128;
  const int wm = (wid >> 1) * 64, wn = (wid & 1) * 64;
  // staging roles: lane -> (row, pre-swizzled chunk) within 8-row slabs
  const int srow = lane >> 3;
  const int schunk = (lane & 7) ^ (srow & 7);
  const int ar0 = (wid >> 1) * 64 + (wid & 1) * 16;  // A stripe-0 slab pair
  const int br0 = wid * 16;                          // B slab pair
  const size_t aG = (size_t)(m0 + ar0 + srow) * 1024 + schunk * 8;
  const size_t bG = (size_t)(n0 + br0 + srow) * 1024 + schunk * 8;

// region select along virtual K' (tile index T of 64): [Xh*Wh|Xh*Wl|Xl*Wh]
#define AREG(T) (((T) < 32) ? Ah_ : Al_)
#define BREG(T) ((((T) >> 4) == 1) ? Bl_ : Bh_)
#define COL(T) ((size_t)((T) & 15) * 64)
#define ST_A0(T, BUF) do { const u16* g_ = AREG(T) + aG + COL(T); \
    glds16(g_, &As[BUF][ar0][0]); glds16(g_ + 8 * 1024, &As[BUF][ar0 + 8][0]); } while (0)
#define ST_A1(T, BUF) do { const u16* g_ = AREG(T) + aG + COL(T) + 32 * 1024; \
    glds16(g_, &As[BUF][ar0 + 32][0]); glds16(g_ + 8 * 1024, &As[BUF][ar0 + 40][0]); } while (0)
#define ST_B(T, BUF) do { const u16* g_ = BREG(T) + bG + COL(T); \
    glds16(g_, &Bs[BUF][br0][0]); glds16(g_ + 8 * 1024, &Bs[BUF][br0 + 8][0]); } while (0)
#define LD_A(BUF, MH) do { _Pragma("unroll") for (int m2 = 0; m2 < 2; m2++) \
    { _Pragma("unroll") for (int kk = 0; kk < 2; kk++) \
      afr[m2][kk] = *(const bf16x8*)&As[BUF][wm + (MH) * 32 + m2 * 16 + lc][((kk * 4 + quad) ^ l7) * 8]; } } while (0)
#define LD_B(BUF) do { _Pragma("unroll") for (int n = 0; n < 4; n++) \
    { _Pragma("unroll") for (int kk = 0; kk < 2; kk++) \
      bfr[n][kk] = *(const bf16x8*)&Bs[BUF][wn + n * 16 + lc][((kk * 4 + quad) ^ l7) * 8]; } } while (0)
#define MM(MH) do { _Pragma("unroll") for (int m2 = 0; m2 < 2; m2++) \
    { _Pragma("unroll") for (int n = 0; n < 4; n++) \
      { _Pragma("unroll") for (int kk = 0; kk < 2; kk++) \
        acc[(MH) * 2 + m2][n] = MFMA(afr[m2][kk], bfr[n][kk], acc[(MH) * 2 + m2][n], 0, 0, 0); } } } while (0)

  f32x4 acc[4][4];
#pragma unroll
  for (int mi = 0; mi < 4; mi++)
#pragma unroll
    for (int ni = 0; ni < 4; ni++) acc[mi][ni] = (f32x4){0.f, 0.f, 0.f, 0.f};
  bf16x8 afr[2][2], bfr[4][2];

  // prologue: t0 fully (6 loads), t1 partial B+A0 (4 loads); A1(t1) in ph1.
  ST_A0(0, 0); ST_A1(0, 0); ST_B(0, 0);
  ST_B(1, 1); ST_A0(1, 1);
  WAITV(4);  // oldest 6 (t0) retired
  BAR();

  const int NI = NT >> 1;
  for (int i = 0; i < NI; ++i) {
    const int t1 = 2 * i + 1, t2 = 2 * i + 2, t3 = 2 * i + 3;
    const bool fin = (t2 >= NT);
    // ph1: read buf0 mh0 + all B; stage A1(t1)->buf1 (str1 freed by prev ph4)
    LD_A(0, 0); LD_B(0);
    ST_A1(t1, 1);
    BAR(); SP(1); MM(0); SP(0); BAR();
    // ph2: read buf0 mh1; stage B,A0(t2)->buf0 (freed after ph1); wait t1
    LD_A(0, 1);
    if (!fin) { ST_B(t2, 0); ST_A0(t2, 0); }
    BAR(); SP(1); MM(1); SP(0);
    if (fin) { WAITV(0); } else { WAITV(4); }  // t1's 6 loads retired
    BAR();
    // ph3: read buf1 mh0 + all B; stage A1(t2)->buf0 (str1 freed after ph2)
    LD_A(1, 0); LD_B(1);
    if (!fin) ST_A1(t2, 0);
    BAR(); SP(1); MM(0); SP(0); BAR();
    // ph4: read buf1 mh1; stage B,A0(t3)->buf1 (freed after ph3); wait t2
    LD_A(1, 1);
    if (!fin) { ST_B(t3, 1); ST_A0(t3, 1); }
    BAR(); SP(1); MM(1); SP(0);
    if (!fin) { WAITV(4); }  // t2's 6 loads retired
    BAR();
  }

  const int rb = quad * 4;
  if (MODE == 1) {
#pragma unroll
    for (int mt = 0; mt < 4; mt++)
#pragma unroll
      for (int nt = 0; nt < 4; nt++)
#pragma unroll
        for (int r = 0; r < 4; r++)
          Cout[(size_t)(m0 + wm + mt * 16 + rb + r) * 1024 + n0 + wn + nt * 16 + lc] =
              acc[mt][nt][r];
    return;
  }
  if (z == 2) {
#pragma unroll
    for (int mt = 0; mt < 4; mt++)
#pragma unroll
      for (int nt = 0; nt < 4; nt++)
#pragma unroll
        for (int r = 0; r < 4; r++) {
          int m = m0 + wm + mt * 16 + rb + r, n = n0 + wn + nt * 16 + lc;
          int b = m >> 11, t = m & 2047, h = n >> 6, d = n & 63;
          Vt[((size_t)(b * 16 + h) * 64 + d) * 2048 + t] = f2bf(acc[mt][nt][r]);
        }
  } else {
    u16* Ch = (z == 0) ? Qh : Kh;
    u16* Cl = (z == 0) ? Ql : Kl;
    const float scale = (z == 0) ? 8.0f : 1.0f;  // fold sqrt(d_k) into Q ONLY
#pragma unroll
    for (int mt = 0; mt < 4; mt++)
#pragma unroll
      for (int nt = 0; nt < 4; nt++)
#pragma unroll
        for (int r = 0; r < 4; r++) {
          int m = m0 + wm + mt * 16 + rb + r, n = n0 + wn + nt * 16 + lc;
          int b = m >> 11, t = m & 2047, h = n >> 6, d = n & 63;
          float v = acc[mt][nt][r] * scale;
          u16 hv = f2bf(v);
          size_t idx = ((size_t)(b * 16 + h) * 2048 + t) * 64 + d;
          Ch[idx] = hv;
          Cl[idx] = f2bf(v - bf2f(hv));
        }
  }
#undef AREG
#undef BREG
#undef COL
#undef ST_A0
#undef ST_A1
#undef ST_B
#undef LD_A
#undef LD_B
#undef MM
}

// ---- flash attention v7: transposed tiles + double-buffered K/V pipeline.
__global__ __launch_bounds__(256, 2) void attn(const u16* __restrict__ Qh,
                                               const u16* __restrict__ Ql,
                                               const u16* __restrict__ Kh,
                                               const u16* __restrict__ Kl,
                                               const u16* __restrict__ Vt,
                                               u16* __restrict__ O16) {
  __shared__ u16 Khs[2][64][64], Kls[2][64][64], Vs[2][64][64];
  __shared__ u16 Ps[4][16][72];  // [wave][query][key-local], 2-way banks (free)
  const int tid = threadIdx.x;
  const int lane = tid & 63, w = tid >> 6;
  const int quad = lane >> 4, lc = lane & 15;
  const int i = blockIdx.x;
  const int bh = i & 31;            // consecutive blocks -> different XCDs
  const int qb = 31 - (i >> 5);     // longest qb first
  const int ng = qb + 1;            // 64-key groups
  const int tq = qb * 64 + w * 16 + lc;  // THIS LANE'S query row
  const size_t kbase = (size_t)bh * 2048 * 64;
  const size_t vbase = (size_t)bh * 64 * 2048;
  const size_t qoff = kbase + (size_t)tq * 64 + quad * 8;
  bf16x8 qh0 = *(const bf16x8*)(Qh + qoff);
  bf16x8 qh1 = *(const bf16x8*)(Qh + qoff + 32);
  bf16x8 ql0 = *(const bf16x8*)(Ql + qoff);
  bf16x8 ql1 = *(const bf16x8*)(Ql + qoff + 32);
  const int srow = lane >> 3;
  const int scol = (lane & 7) ^ srow;
  const u16* kg0 = Kh + kbase + (size_t)(w * 16 + srow) * 64 + scol * 8;
  const u16* lg0 = Kl + kbase + (size_t)(w * 16 + srow) * 64 + scol * 8;
  const u16* vg0 = Vt + vbase + (size_t)(w * 16 + srow) * 2048 + scol * 8;

  float mi = -3.0e38f, li = 0.f;
  f32x4 o[4];
#pragma unroll
  for (int d = 0; d < 4; d++) o[d] = (f32x4){0.f, 0.f, 0.f, 0.f};
  const int rx = lc & 7;  // read-side XOR component (row&7 = lc&7)

  {
    glds16(kg0, &Khs[0][w * 16][0]); glds16(kg0 + 8 * 64, &Khs[0][w * 16 + 8][0]);
    glds16(lg0, &Kls[0][w * 16][0]); glds16(lg0 + 8 * 64, &Kls[0][w * 16 + 8][0]);
    glds16(vg0, &Vs[0][w * 16][0]);  glds16(vg0 + 8 * 2048, &Vs[0][w * 16 + 8][0]);
  }
  for (int g = 0; g < ng; g++) {
    const int buf = g & 1;
    const int z0 = g * 64;
    __syncthreads();  // drains glds(g); all waves done reading buf^1
    if (g + 1 < ng) {
      const int zn = (g + 1) * 64;
      const int nb = buf ^ 1;
      glds16(kg0 + (size_t)zn * 64, &Khs[nb][w * 16][0]);
      glds16(kg0 + (size_t)zn * 64 + 8 * 64, &Khs[nb][w * 16 + 8][0]);
      glds16(lg0 + (size_t)zn * 64, &Kls[nb][w * 16][0]);
      glds16(lg0 + (size_t)zn * 64 + 8 * 64, &Kls[nb][w * 16 + 8][0]);
      glds16(vg0 + zn, &Vs[nb][w * 16][0]);
      glds16(vg0 + zn + 8 * 2048, &Vs[nb][w * 16 + 8][0]);
    }
    f32x4 s[4];
#pragma unroll
    for (int tt = 0; tt < 4; tt++) {
      const int R = tt * 16 + lc;
      bf16x8 kh0 = *(const bf16x8*)&Khs[buf][R][(quad ^ rx) * 8];
      bf16x8 kh1 = *(const bf16x8*)&Khs[buf][R][((4 + quad) ^ rx) * 8];
      bf16x8 kl0 = *(const bf16x8*)&Kls[buf][R][(quad ^ rx) * 8];
      bf16x8 kl1 = *(const bf16x8*)&Kls[buf][R][((4 + quad) ^ rx) * 8];
      f32x4 sv = (f32x4){0.f, 0.f, 0.f, 0.f};
      sv = MFMA(kh0, qh0, sv, 0, 0, 0);
      sv = MFMA(kh1, qh1, sv, 0, 0, 0);
      sv = MFMA(kh0, ql0, sv, 0, 0, 0);
      sv = MFMA(kh1, ql1, sv, 0, 0, 0);
      sv = MFMA(kl0, qh0, sv, 0, 0, 0);
      sv = MFMA(kl1, qh1, sv, 0, 0, 0);
      s[tt] = sv;
    }
    if (g == ng - 1) {
#pragma unroll
      for (int tt = 0; tt < 4; tt++)
#pragma unroll
        for (int r = 0; r < 4; r++)
          if (z0 + tt * 16 + quad * 4 + r > tq) s[tt][r] = -3.0e38f;
    }
    float smax = -3.0e38f;
#pragma unroll
    for (int tt = 0; tt < 4; tt++)
#pragma unroll
      for (int r = 0; r < 4; r++) smax = fmaxf(smax, s[tt][r]);
    smax = fmaxf(smax, __shfl_xor(smax, 16));
    smax = fmaxf(smax, __shfl_xor(smax, 32));
    float mnew = fmaxf(mi, smax);
    float alpha = __expf(mi - mnew);
    mi = mnew;
    float rs = 0.f;
#pragma unroll
    for (int tt = 0; tt < 4; tt++) {
      union { u16 h[4]; u64 d; } pk;
#pragma unroll
      for (int r = 0; r < 4; r++) {
        float p = __expf(s[tt][r] - mnew);
        rs += p;
        pk.h[r] = f2bf(p);
      }
      *(u64*)&Ps[w][lc][tt * 16 + quad * 4] = pk.d;
    }
    li = li * alpha + rs;
#pragma unroll
    for (int d = 0; d < 4; d++) o[d] *= alpha;
    bf16x8 pf0 = *(const bf16x8*)&Ps[w][lc][quad * 8];
    bf16x8 pf1 = *(const bf16x8*)&Ps[w][lc][32 + quad * 8];
#pragma unroll
    for (int dd = 0; dd < 4; dd++) {
      const int R = dd * 16 + lc;
      bf16x8 va0 = *(const bf16x8*)&Vs[buf][R][(quad ^ rx) * 8];
      bf16x8 va1 = *(const bf16x8*)&Vs[buf][R][((4 + quad) ^ rx) * 8];
      o[dd] = MFMA(va0, pf0, o[dd], 0, 0, 0);
      o[dd] = MFMA(va1, pf1, o[dd], 0, 0, 0);
    }
  }
  li += __shfl_xor(li, 16);
  li += __shfl_xor(li, 32);
  const float rli = 1.0f / li;
  const int b = bh >> 4, hh = bh & 15;
  const size_t obase = ((size_t)(b * 2048 + tq)) * 1024 + hh * 64 + quad * 4;
#pragma unroll
  for (int dd = 0; dd < 4; dd++) {
    ushort4 ov;
    ov.x = f2bf(o[dd][0] * rli);
    ov.y = f2bf(o[dd][1] * rli);
    ov.z = f2bf(o[dd][2] * rli);
    ov.w = f2bf(o[dd][3] * rli);
    *(ushort4*)&O16[obase + dd * 16] = ov;
  }
}

extern "C" void kernel_launch(void* const* d_in, const int* in_sizes, int n_in,
                              void* d_out, int out_size, void* d_ws, size_t ws_size,
                              hipStream_t stream) {
  const float* x  = (const float*)d_in[0];
  const float* wq = (const float*)d_in[1];
  const float* wk = (const float*)d_in[2];
  const float* wv = (const float*)d_in[3];
  const float* wo = (const float*)d_in[4];

  char* w = (char*)d_ws;
  const size_t MB = 1u << 20;
  u16* Xh  = (u16*)(w + 0 * MB);   // 8MB; dead after projections -> O16 reuses
  u16* Xl  = (u16*)(w + 8 * MB);
  u16* Wqh = (u16*)(w + 16 * MB);
  u16* Wql = (u16*)(w + 18 * MB);
  u16* Wkh = (u16*)(w + 20 * MB);
  u16* Wkl = (u16*)(w + 22 * MB);
  u16* Wvt = (u16*)(w + 24 * MB);
  u16* Wot = (u16*)(w + 26 * MB);
  u16* Qhb = (u16*)(w + 28 * MB);  // [32][2048][64] bf16
  u16* Qlb = (u16*)(w + 36 * MB);
  u16* Khb = (u16*)(w + 44 * MB);
  u16* Klb = (u16*)(w + 52 * MB);
  u16* Vtb = (u16*)(w + 60 * MB);  // [32][64][2048] bf16
  u16* O16 = (u16*)(w + 0 * MB);   // reuse Xh region

  hipLaunchKernelGGL(prep, dim3(32, 32, 5), dim3(256), 0, stream,
                     x, wq, wk, wv, wo, Xh, Xl, Wqh, Wql, Wkh, Wkl, Wvt, Wot);

  hipLaunchKernelGGL(HIP_KERNEL_NAME(gemm3<0>), dim3(8, 16, 3), dim3(512), 0, stream,
                     Xh, Xl, Wqh, Wql, Wkh, Wkl, Wvt,
                     Qhb, Qlb, Khb, Klb, Vtb, (float*)nullptr);

  hipLaunchKernelGGL(attn, dim3(1024), dim3(256), 0, stream,
                     Qhb, Qlb, Khb, Klb, Vtb, O16);

  hipLaunchKernelGGL(HIP_KERNEL_NAME(gemm3<1>), dim3(8, 16, 1), dim3(512), 0, stream,
                     O16, O16, Wot, Wot, Wot, Wot, Wot,
                     (u16*)nullptr, (u16*)nullptr, (u16*)nullptr, (u16*)nullptr,
                     (u16*)nullptr, (float*)d_out);
}